// Round 1
// baseline (865.083 us; speedup 1.0000x reference)
//
#include <hip/hip_runtime.h>
#include <hip/hip_bf16.h>

#define MROWS 4096      // B*T
#define KDIM 1024       // H
#define NVOCAB 32000    // V
#define BM 128
#define BN 128
#define BK 32
#define NTILES (NVOCAB / BN)   // 250
#define MTILES (MROWS / BM)    // 32
#define BETA 0.1f

typedef __attribute__((ext_vector_type(8))) short s8v;
typedef __attribute__((ext_vector_type(4))) float f4v;

__device__ inline void gload16(const void* g, void* l) {
  __builtin_amdgcn_global_load_lds(
      (const __attribute__((address_space(1))) void*)g,
      (__attribute__((address_space(3))) void*)l, 16, 0, 0);
}

__device__ inline unsigned bf16pair(float lo, float hi) {
  unsigned a = __float_as_uint(lo), b = __float_as_uint(hi);
  a = (a + 0x7FFFu + ((a >> 16) & 1u)) >> 16;
  b = (b + 0x7FFFu + ((b >> 16) & 1u)) >> 16;
  return a | (b << 16);
}

// fp32 -> bf16 (RNE), 8 elems/thread
__global__ void cvt8(const float4* __restrict__ in, uint4* __restrict__ out, int n8) {
  int i = blockIdx.x * 256 + threadIdx.x;
  if (i >= n8) return;
  float4 a = in[2 * i], b = in[2 * i + 1];
  uint4 o;
  o.x = bf16pair(a.x, a.y);
  o.y = bf16pair(a.z, a.w);
  o.z = bf16pair(b.x, b.y);
  o.w = bf16pair(b.z, b.w);
  out[i] = o;
}

// GEMM + fused per-tile logsumexp partials + target-logit gather.
// grid = (NTILES, MTILES, 2 models), block = 256 (4 waves, 2x2, 64x64 each)
__global__ __launch_bounds__(256, 2) void gemm_lse(
    const __hip_bfloat16* __restrict__ xb, const __hip_bfloat16* __restrict__ rxb,
    const __hip_bfloat16* __restrict__ Wb, const __hip_bfloat16* __restrict__ rWb,
    const int* __restrict__ y,
    float2* __restrict__ partials,  // [2][NTILES][MROWS]
    float* __restrict__ tgt)        // [2][MROWS]
{
  const int bx = blockIdx.x;  // vocab tile
  const int by = blockIdx.y;  // row tile
  const int bz = blockIdx.z;  // model
  const __hip_bfloat16* A  = bz ? rxb : xb;
  const __hip_bfloat16* Bw = bz ? rWb : Wb;

  const int tid = threadIdx.x;
  const int lane = tid & 63;
  const int w = tid >> 6;
  const int wr = w >> 1, wc = w & 1;
  const int l15 = lane & 15, l4 = lane >> 4;

  const int m0 = by * BM;
  const int n0 = bx * BN;

  __shared__ __align__(16) short As[BM * BK];
  __shared__ __align__(16) short Bs[BN * BK];
  __shared__ int ys[BM];
  __shared__ float redM[2][BM];
  __shared__ float redS[2][BM];

  if (tid < BM) ys[tid] = y[m0 + tid];

  f4v acc[4][4];
#pragma unroll
  for (int i = 0; i < 4; ++i)
#pragma unroll
    for (int j = 0; j < 4; ++j) acc[i][j] = (f4v){0.f, 0.f, 0.f, 0.f};

  // staging addresses: chunk q covers row q>>2, 8 bf16 at (q&3)*8
  const __hip_bfloat16* aSrc0 = A  + (size_t)(m0 + (tid >> 2)) * KDIM + (tid & 3) * 8;
  const __hip_bfloat16* aSrc1 = A  + (size_t)(m0 + 64 + (tid >> 2)) * KDIM + (tid & 3) * 8;
  const __hip_bfloat16* bSrc0 = Bw + (size_t)(n0 + (tid >> 2)) * KDIM + (tid & 3) * 8;
  const __hip_bfloat16* bSrc1 = Bw + (size_t)(n0 + 64 + (tid >> 2)) * KDIM + (tid & 3) * 8;
  short* aDst0 = &As[tid * 8];
  short* aDst1 = &As[(tid + 256) * 8];
  short* bDst0 = &Bs[tid * 8];
  short* bDst1 = &Bs[(tid + 256) * 8];

  for (int kt = 0; kt < KDIM / BK; ++kt) {
    gload16(aSrc0, aDst0);
    gload16(aSrc1, aDst1);
    gload16(bSrc0, bDst0);
    gload16(bSrc1, bDst1);
    aSrc0 += BK; aSrc1 += BK; bSrc0 += BK; bSrc1 += BK;
    __syncthreads();  // drains vmcnt before barrier (compiler-inserted)

    s8v afr[4], bfr[4];
#pragma unroll
    for (int mi = 0; mi < 4; ++mi)
      afr[mi] = *reinterpret_cast<const s8v*>(&As[(wr * 64 + mi * 16 + l15) * BK + l4 * 8]);
#pragma unroll
    for (int ni = 0; ni < 4; ++ni)
      bfr[ni] = *reinterpret_cast<const s8v*>(&Bs[(wc * 64 + ni * 16 + l15) * BK + l4 * 8]);
#pragma unroll
    for (int mi = 0; mi < 4; ++mi)
#pragma unroll
      for (int ni = 0; ni < 4; ++ni)
        acc[mi][ni] = __builtin_amdgcn_mfma_f32_16x16x32_bf16(afr[mi], bfr[ni], acc[mi][ni], 0, 0, 0);
    __syncthreads();
  }

  // Epilogue: per-row (max, sumexp) over this block's 128 cols + target gather.
  // D layout: row = (l>>4)*4 + r (+ mi*16 + wr*64), col = l&15 (+ ni*16 + wc*64)
#pragma unroll
  for (int mi = 0; mi < 4; ++mi) {
#pragma unroll
    for (int r = 0; r < 4; ++r) {
      float v0 = acc[mi][0][r], v1 = acc[mi][1][r], v2 = acc[mi][2][r], v3 = acc[mi][3][r];
      float mx = fmaxf(fmaxf(v0, v1), fmaxf(v2, v3));
#pragma unroll
      for (int d = 1; d < 16; d <<= 1) mx = fmaxf(mx, __shfl_xor(mx, d));
      float ex = __expf(v0 - mx) + __expf(v1 - mx) + __expf(v2 - mx) + __expf(v3 - mx);
#pragma unroll
      for (int d = 1; d < 16; d <<= 1) ex += __shfl_xor(ex, d);
      int rowInBlock = wr * 64 + mi * 16 + l4 * 4 + r;
      if (l15 == 0) { redM[wc][rowInBlock] = mx; redS[wc][rowInBlock] = ex; }
      // target logit: exactly one block/lane owns (row, y[row])
      int yv = ys[rowInBlock];
      int cl = yv - (n0 + wc * 64);
      if (cl >= 0 && cl < 64 && (cl & 15) == l15) {
        int nsel = cl >> 4;
        float tv = nsel == 0 ? acc[mi][0][r] : nsel == 1 ? acc[mi][1][r]
                 : nsel == 2 ? acc[mi][2][r] : acc[mi][3][r];
        tgt[(size_t)bz * MROWS + m0 + rowInBlock] = tv;
      }
    }
  }
  __syncthreads();
  if (tid < BM) {
    float ma = redM[0][tid], mb = redM[1][tid];
    float sa = redS[0][tid], sb = redS[1][tid];
    float M = fmaxf(ma, mb);
    float S = sa * __expf(ma - M) + sb * __expf(mb - M);
    partials[((size_t)bz * NTILES + bx) * MROWS + m0 + tid] = make_float2(M, S);
  }
}

// merge partials per row -> lse -> per-example mean target logp
__global__ void rowred(const float2* __restrict__ partials, const float* __restrict__ tgt,
                       const int* __restrict__ y, float* __restrict__ logps) {
  const int model = blockIdx.x >> 2;
  const int b = blockIdx.x & 3;
  const int tid = threadIdx.x;
  float sum = 0.f, cnt = 0.f;
  for (int t = tid; t < 1024; t += 256) {
    const int row = b * 1024 + t;
    float M = -INFINITY, S = 0.f;
    for (int j = 0; j < NTILES; ++j) {
      float2 v = partials[((size_t)model * NTILES + j) * MROWS + row];
      float Mn = fmaxf(M, v.x);
      S = S * __expf(M - Mn) + v.y * __expf(v.x - Mn);
      M = Mn;
    }
    int yv = y[row];
    if (yv != -100) {
      sum += tgt[(size_t)model * MROWS + row] - (M + __logf(S));
      cnt += 1.f;
    }
  }
  __shared__ float sS[4], sC[4];
#pragma unroll
  for (int d = 1; d < 64; d <<= 1) { sum += __shfl_xor(sum, d); cnt += __shfl_xor(cnt, d); }
  int w = tid >> 6;
  if ((tid & 63) == 0) { sS[w] = sum; sC[w] = cnt; }
  __syncthreads();
  if (tid == 0) {
    float s = 0.f, c = 0.f;
    for (int i = 0; i < 4; ++i) { s += sS[i]; c += sC[i]; }
    logps[blockIdx.x] = s / c;
  }
}

__global__ void finalk(const float* __restrict__ logps, const int* __restrict__ pref,
                       float* __restrict__ out) {
  if (threadIdx.x == 0 && blockIdx.x == 0) {
    float acc = 0.f;
    for (int b = 0; b < 4; ++b) {
      float lr = logps[b] - logps[4 + b];   // policy - ref
      float z = BETA * lr;
      float sig = 1.f / (1.f + __expf(-z));
      float chosen = 1.f - sig;
      float rejected = sig;                 // 1 - sigmoid(-z)
      acc += (pref[b] != 0) ? chosen : rejected;
    }
    out[0] = acc * 0.25f;
  }
}

extern "C" void kernel_launch(void* const* d_in, const int* in_sizes, int n_in,
                              void* d_out, int out_size, void* d_ws, size_t ws_size,
                              hipStream_t stream) {
  const float* x    = (const float*)d_in[0];
  const float* rx   = (const float*)d_in[1];
  const int*   y    = (const int*)d_in[2];
  const int*   pref = (const int*)d_in[3];
  const float* W    = (const float*)d_in[4];
  const float* rW   = (const float*)d_in[5];
  float* out = (float*)d_out;

  char* ws = (char*)d_ws;
  const size_t SZ_X = (size_t)MROWS * KDIM * 2;        // 8,388,608
  const size_t SZ_W = (size_t)NVOCAB * KDIM * 2;       // 65,536,000
  __hip_bfloat16* xb   = (__hip_bfloat16*)(ws);
  __hip_bfloat16* rxb  = (__hip_bfloat16*)(ws + SZ_X);
  __hip_bfloat16* Wb   = (__hip_bfloat16*)(ws + 2 * SZ_X);
  __hip_bfloat16* rWb  = (__hip_bfloat16*)(ws + 2 * SZ_X + SZ_W);
  float2* partials = (float2*)(ws + 2 * SZ_X + 2 * SZ_W);
  float*  tgt      = (float*)(ws + 2 * SZ_X + 2 * SZ_W + (size_t)2 * NTILES * MROWS * 8);
  float*  logps    = (float*)(ws + 2 * SZ_X + 2 * SZ_W + (size_t)2 * NTILES * MROWS * 8 + 2 * MROWS * 4);

  const int n8x = MROWS * KDIM / 8;     // 524288
  const int n8w = NVOCAB * KDIM / 8;    // 4096000
  cvt8<<<dim3((n8x + 255) / 256), 256, 0, stream>>>((const float4*)x,  (uint4*)xb,  n8x);
  cvt8<<<dim3((n8x + 255) / 256), 256, 0, stream>>>((const float4*)rx, (uint4*)rxb, n8x);
  cvt8<<<dim3((n8w + 255) / 256), 256, 0, stream>>>((const float4*)W,  (uint4*)Wb,  n8w);
  cvt8<<<dim3((n8w + 255) / 256), 256, 0, stream>>>((const float4*)rW, (uint4*)rWb, n8w);

  gemm_lse<<<dim3(NTILES, MTILES, 2), 256, 0, stream>>>(xb, rxb, Wb, rWb, y, partials, tgt);
  rowred<<<dim3(8), 256, 0, stream>>>(partials, tgt, y, logps);
  finalk<<<dim3(1), 64, 0, stream>>>(logps, pref, out);
}

// Round 2
// 841.422 us; speedup vs baseline: 1.0281x; 1.0281x over previous
//
#include <hip/hip_runtime.h>
#include <hip/hip_bf16.h>

#define MROWS 4096      // B*T
#define KDIM 1024       // H
#define NVOCAB 32000    // V
#define BM 256
#define BN 256
#define BK 64
#define NTILES (NVOCAB / BN)   // 125
#define MTILES (MROWS / BM)    // 16
#define KT (KDIM / BK)         // 16
#define BETA 0.1f

typedef __attribute__((ext_vector_type(8))) short s8v;
typedef __attribute__((ext_vector_type(4))) float f4v;

__device__ inline void gload16(const void* g, void* l) {
  __builtin_amdgcn_global_load_lds(
      (const __attribute__((address_space(1))) void*)g,
      (__attribute__((address_space(3))) void*)l, 16, 0, 0);
}

__device__ inline unsigned bf16pair(float lo, float hi) {
  unsigned a = __float_as_uint(lo), b = __float_as_uint(hi);
  a = (a + 0x7FFFu + ((a >> 16) & 1u)) >> 16;
  b = (b + 0x7FFFu + ((b >> 16) & 1u)) >> 16;
  return a | (b << 16);
}

// fused fp32 -> bf16 (RNE) for all 4 tensors, grid-stride, 16B/load
__global__ void cvt_all(const float4* __restrict__ x, const float4* __restrict__ rx,
                        const float4* __restrict__ W, const float4* __restrict__ rW,
                        uint4* __restrict__ xb, uint4* __restrict__ rxb,
                        uint4* __restrict__ Wb, uint4* __restrict__ rWb) {
  const int NX = MROWS * KDIM / 8;      // 524288
  const int NW = NVOCAB * KDIM / 8;     // 4096000
  const int total = 2 * NX + 2 * NW;
  for (int i = blockIdx.x * 256 + threadIdx.x; i < total; i += gridDim.x * 256) {
    const float4* s; uint4* d; int j;
    if (i < NX)               { s = x;  d = xb;  j = i; }
    else if (i < 2 * NX)      { s = rx; d = rxb; j = i - NX; }
    else if (i < 2 * NX + NW) { s = W;  d = Wb;  j = i - 2 * NX; }
    else                      { s = rW; d = rWb; j = i - 2 * NX - NW; }
    float4 a = s[2 * j], b = s[2 * j + 1];
    uint4 o;
    o.x = bf16pair(a.x, a.y);
    o.y = bf16pair(a.z, a.w);
    o.z = bf16pair(b.x, b.y);
    o.w = bf16pair(b.z, b.w);
    d[j] = o;
  }
}

// swizzled LDS fragment read: row stride 128 B, byte ^= (row&7)<<4
__device__ inline s8v ldsfrag(const short* S, int row, int ks, int l4) {
  int byte = row * 128 + ks * 64 + l4 * 16;
  byte ^= (row & 7) << 4;
  return *reinterpret_cast<const s8v*>(reinterpret_cast<const char*>(S) + byte);
}

// 256x256 GEMM tile + fused per-tile logsumexp partials + target-logit gather.
// grid = (2000, 2 models), block = 512 (8 waves, 2x4, each 128x64 output)
__global__ __launch_bounds__(512, 2) void gemm_lse(
    const __hip_bfloat16* __restrict__ xb, const __hip_bfloat16* __restrict__ rxb,
    const __hip_bfloat16* __restrict__ Wb, const __hip_bfloat16* __restrict__ rWb,
    const int* __restrict__ y,
    float2* __restrict__ partials,  // [2][NTILES][MROWS]
    float* __restrict__ tgt)        // [2][MROWS]
{
  const int bid = blockIdx.x;       // 0..1999
  const int bz  = blockIdx.y;       // model
  // 2-D XCD chunking: each XCD sweeps a 4-mtile band across all ntiles
  const int lin   = (bid & 7) * 250 + (bid >> 3);
  const int mg    = lin / 500;
  const int rem   = lin % 500;
  const int ntile = rem >> 2;
  const int mtile = mg * 4 + (rem & 3);
  const int m0 = mtile * BM, n0 = ntile * BN;

  const __hip_bfloat16* A  = bz ? rxb : xb;
  const __hip_bfloat16* Bw = bz ? rWb : Wb;

  const int tid = threadIdx.x;
  const int lane = tid & 63;
  const int w = tid >> 6;            // 0..7
  const int wr = w >> 2, wc = w & 3; // 2 x 4 wave grid
  const int l15 = lane & 15, l4 = lane >> 4;

  __shared__ __align__(16) short As[2][BM * BK];
  __shared__ __align__(16) short Bs[2][BM * BK];
  __shared__ int ys[BM];
  __shared__ float redM[4][BM];
  __shared__ float redS[4][BM];

  if (tid < BM) ys[tid] = y[m0 + tid];

  f4v acc[8][4];
#pragma unroll
  for (int i = 0; i < 8; ++i)
#pragma unroll
    for (int j = 0; j < 4; ++j) acc[i][j] = (f4v){0.f, 0.f, 0.f, 0.f};

  // staging map: chunk c = j*512+tid covers LDS bytes [c*16, c*16+16) (linear dest).
  // LDS slot (c&7) of row (c>>3) must hold global col-chunk (c&7)^(row&7)  (inverse swizzle).
  int arow[4], acs[4];
#pragma unroll
  for (int j = 0; j < 4; ++j) {
    int c = j * 512 + tid;
    arow[j] = c >> 3;
    acs[j] = ((c & 7) ^ (arow[j] & 7)) * 8;
  }

#define STAGE(kt, buf)                                                              \
  {                                                                                 \
    _Pragma("unroll")                                                               \
    for (int j = 0; j < 4; ++j)                                                     \
      gload16(A + (size_t)(m0 + arow[j]) * KDIM + (kt) * BK + acs[j],               \
              &As[buf][(j * 512 + tid) * 8]);                                       \
    _Pragma("unroll")                                                               \
    for (int j = 0; j < 4; ++j)                                                     \
      gload16(Bw + (size_t)(n0 + arow[j]) * KDIM + (kt) * BK + acs[j],              \
              &Bs[buf][(j * 512 + tid) * 8]);                                       \
  }

  // prologue: tiles 0 and 1 in flight; full drain once
  STAGE(0, 0);
  STAGE(1, 1);
  __syncthreads();

  for (int t = 0; t < KT; ++t) {
    const int cur = t & 1;
    if (t >= 1 && t + 1 < KT) STAGE(t + 1, cur ^ 1);  // issued 4 phases before needed
    const short* Sa = As[cur];
    const short* Sb = Bs[cur];
#pragma unroll
    for (int q = 0; q < 4; ++q) {          // 4 phases x 16 MFMA
      const int mh = (q >> 1) * 4, np = (q & 1) * 2;
      s8v af[4][2], bf[2][2];
#pragma unroll
      for (int mi = 0; mi < 4; ++mi)
#pragma unroll
        for (int ks = 0; ks < 2; ++ks)
          af[mi][ks] = ldsfrag(Sa, wr * 128 + (mh + mi) * 16 + l15, ks, l4);
#pragma unroll
      for (int ni = 0; ni < 2; ++ni)
#pragma unroll
        for (int ks = 0; ks < 2; ++ks)
          bf[ni][ks] = ldsfrag(Sb, wc * 64 + (np + ni) * 16 + l15, ks, l4);
      __builtin_amdgcn_s_setprio(1);
#pragma unroll
      for (int mi = 0; mi < 4; ++mi)
#pragma unroll
        for (int ni = 0; ni < 2; ++ni)
#pragma unroll
          for (int ks = 0; ks < 2; ++ks)
            acc[mh + mi][np + ni] = __builtin_amdgcn_mfma_f32_16x16x32_bf16(
                af[mi][ks], bf[ni][ks], acc[mh + mi][np + ni], 0, 0, 0);
      __builtin_amdgcn_s_setprio(0);
    }
    __syncthreads();  // drains vmcnt: tile t+1's loads had ~4 phases of slack
  }

  // Epilogue: per-row (max, sumexp) over this block's 256 cols + target gather.
  // D layout: row = wr*128 + mi*16 + l4*4 + r, col = wc*64 + ni*16 + l15
#pragma unroll
  for (int mi = 0; mi < 8; ++mi) {
#pragma unroll
    for (int r = 0; r < 4; ++r) {
      float v0 = acc[mi][0][r], v1 = acc[mi][1][r], v2 = acc[mi][2][r], v3 = acc[mi][3][r];
      float mx = fmaxf(fmaxf(v0, v1), fmaxf(v2, v3));
#pragma unroll
      for (int d = 1; d < 16; d <<= 1) mx = fmaxf(mx, __shfl_xor(mx, d));
      float ex = __expf(v0 - mx) + __expf(v1 - mx) + __expf(v2 - mx) + __expf(v3 - mx);
#pragma unroll
      for (int d = 1; d < 16; d <<= 1) ex += __shfl_xor(ex, d);
      int rowInBlock = wr * 128 + mi * 16 + l4 * 4 + r;
      if (l15 == 0) { redM[wc][rowInBlock] = mx; redS[wc][rowInBlock] = ex; }
      int yv = ys[rowInBlock];
      int cl = yv - (n0 + wc * 64);
      if (cl >= 0 && cl < 64 && (cl & 15) == l15) {
        int ni = cl >> 4;
        float tv = ni == 0 ? v0 : ni == 1 ? v1 : ni == 2 ? v2 : v3;
        tgt[(size_t)bz * MROWS + m0 + rowInBlock] = tv;
      }
    }
  }
  __syncthreads();
  if (tid < BM) {
    float M = redM[0][tid], S = redS[0][tid];
#pragma unroll
    for (int c = 1; c < 4; ++c) {
      float m2 = redM[c][tid], s2 = redS[c][tid];
      float Mn = fmaxf(M, m2);
      S = S * __expf(M - Mn) + s2 * __expf(m2 - Mn);
      M = Mn;
    }
    partials[((size_t)bz * NTILES + ntile) * MROWS + m0 + tid] = make_float2(M, S);
  }
#undef STAGE
}

// merge partials per row -> lse -> per-example mean target logp
__global__ void rowred(const float2* __restrict__ partials, const float* __restrict__ tgt,
                       const int* __restrict__ y, float* __restrict__ logps) {
  const int model = blockIdx.x >> 2;
  const int b = blockIdx.x & 3;
  const int tid = threadIdx.x;
  float sum = 0.f, cnt = 0.f;
  for (int t = tid; t < 1024; t += 256) {
    const int row = b * 1024 + t;
    float M = -INFINITY, S = 0.f;
    for (int j = 0; j < NTILES; ++j) {
      float2 v = partials[((size_t)model * NTILES + j) * MROWS + row];
      float Mn = fmaxf(M, v.x);
      S = S * __expf(M - Mn) + v.y * __expf(v.x - Mn);
      M = Mn;
    }
    int yv = y[row];
    if (yv != -100) {
      sum += tgt[(size_t)model * MROWS + row] - (M + __logf(S));
      cnt += 1.f;
    }
  }
  __shared__ float sS[4], sC[4];
#pragma unroll
  for (int d = 1; d < 64; d <<= 1) { sum += __shfl_xor(sum, d); cnt += __shfl_xor(cnt, d); }
  int w = tid >> 6;
  if ((tid & 63) == 0) { sS[w] = sum; sC[w] = cnt; }
  __syncthreads();
  if (tid == 0) {
    float s = 0.f, c = 0.f;
    for (int i = 0; i < 4; ++i) { s += sS[i]; c += sC[i]; }
    logps[blockIdx.x] = s / c;
  }
}

__global__ void finalk(const float* __restrict__ logps, const int* __restrict__ pref,
                       float* __restrict__ out) {
  if (threadIdx.x == 0 && blockIdx.x == 0) {
    float acc = 0.f;
    for (int b = 0; b < 4; ++b) {
      float lr = logps[b] - logps[4 + b];   // policy - ref
      float z = BETA * lr;
      float sig = 1.f / (1.f + __expf(-z));
      acc += (pref[b] != 0) ? (1.f - sig) : sig;
    }
    out[0] = acc * 0.25f;
  }
}

extern "C" void kernel_launch(void* const* d_in, const int* in_sizes, int n_in,
                              void* d_out, int out_size, void* d_ws, size_t ws_size,
                              hipStream_t stream) {
  const float* x    = (const float*)d_in[0];
  const float* rx   = (const float*)d_in[1];
  const int*   y    = (const int*)d_in[2];
  const int*   pref = (const int*)d_in[3];
  const float* W    = (const float*)d_in[4];
  const float* rW   = (const float*)d_in[5];
  float* out = (float*)d_out;

  char* ws = (char*)d_ws;
  const size_t SZ_X = (size_t)MROWS * KDIM * 2;        // 8,388,608
  const size_t SZ_W = (size_t)NVOCAB * KDIM * 2;       // 65,536,000
  __hip_bfloat16* xb   = (__hip_bfloat16*)(ws);
  __hip_bfloat16* rxb  = (__hip_bfloat16*)(ws + SZ_X);
  __hip_bfloat16* Wb   = (__hip_bfloat16*)(ws + 2 * SZ_X);
  __hip_bfloat16* rWb  = (__hip_bfloat16*)(ws + 2 * SZ_X + SZ_W);
  float2* partials = (float2*)(ws + 2 * SZ_X + 2 * SZ_W);
  float*  tgt      = (float*)(ws + 2 * SZ_X + 2 * SZ_W + (size_t)2 * NTILES * MROWS * 8);
  float*  logps    = (float*)(ws + 2 * SZ_X + 2 * SZ_W + (size_t)2 * NTILES * MROWS * 8 + 2 * MROWS * 4);

  cvt_all<<<dim3(2048), 256, 0, stream>>>((const float4*)x, (const float4*)rx,
                                          (const float4*)W, (const float4*)rW,
                                          (uint4*)xb, (uint4*)rxb, (uint4*)Wb, (uint4*)rWb);

  gemm_lse<<<dim3(2000, 2), 512, 0, stream>>>(xb, rxb, Wb, rWb, y, partials, tgt);
  rowred<<<dim3(8), 256, 0, stream>>>(partials, tgt, y, logps);
  finalk<<<dim3(1), 64, 0, stream>>>(logps, pref, out);
}